// Round 3
// baseline (466.195 us; speedup 1.0000x reference)
//
#include <hip/hip_runtime.h>

#define HH 51
#define TT 256
#define NB 16
#define L2E 1.442695041f

typedef __attribute__((ext_vector_type(8))) _Float16 half8;
typedef __attribute__((ext_vector_type(4))) float   floatx4;

#define MFMA16F(A,B,C) __builtin_amdgcn_mfma_f32_16x16x32_f16((A),(B),(C),0,0,0)

__device__ __forceinline__ float rcp_fast(float x) { return __builtin_amdgcn_rcpf(x); }
#if __has_builtin(__builtin_amdgcn_exp2f)
__device__ __forceinline__ float exp2_fast(float x) { return __builtin_amdgcn_exp2f(x); }
#else
__device__ __forceinline__ float exp2_fast(float x) { return __expf(0.69314718056f * x); }
#endif
__device__ __forceinline__ unsigned short f2h_bits(float v) {
    return __builtin_bit_cast(unsigned short, (_Float16)v);
}

// ------------- weight pre-pack: fp16 hi/lo fragments, K-column folding ---
// (UNCHANGED; layout comments from the 377us version still apply.)
__global__ void lstm_prep(const float* __restrict__ Whh1, const float* __restrict__ Wih1,
                          const float* __restrict__ bih1, const float* __restrict__ bhh1,
                          const float* __restrict__ Wih2, const float* __restrict__ Whh2,
                          const float* __restrict__ bih2, const float* __restrict__ bhh2,
                          const float* __restrict__ Wlin, const float* __restrict__ blin,
                          uint4* __restrict__ frags) {
    int tid = blockIdx.x * blockDim.x + threadIdx.x;
    if (tid >= 196 * 64) return;
    int f = tid >> 6, lane = tid & 63;
    int n = lane & 15, qq = lane >> 4;
    int hl, s, tau, cell;
    if (f < 64)       { cell = 1; int r = f;       hl = r & 1; r >>= 1; s = r & 1; tau = r >> 1; }
    else if (f < 192) { cell = 2; int r = f - 64;  hl = r & 1; r >>= 1; s = r & 3; tau = r >> 2; }
    else              { cell = 3; int r = f - 192; hl = r & 1; s = r >> 1; tau = 0; }
    int g = tau >> 2, U = tau & 3, u = U * 16 + n;
    float sc = (cell == 3) ? 1.0f : ((g == 2) ? 2.0f * L2E : L2E);
    unsigned int dw[4];
    for (int d = 0; d < 4; d++) {
        unsigned int packed = 0;
        for (int e = 0; e < 2; e++) {
            int jj = d * 2 + e;
            int k = s * 32 + qq * 8 + jj;
            float val = 0.f;
            if (cell == 1) {
                if (u < HH) {
                    if (k < HH)       val = Whh1[(g * HH + u) * HH + k];
                    else if (k == 51) val = bih1[g * HH + u] + bhh1[g * HH + u];
                    else              val = Wih1[g * HH + u];   // k=52,53
                }
            } else if (cell == 2) {
                if (u < HH) {
                    if (k < 64) {
                        if (k < HH)       val = Wih2[(g * HH + u) * HH + k];
                        else if (k == 51) val = bih2[g * HH + u] + bhh2[g * HH + u];
                        // k=52,53 stay 0 (x pass-through)
                    } else {
                        int k2 = k - 64;
                        if (k2 < HH) val = Whh2[(g * HH + u) * HH + k2];
                    }
                }
            } else {
                if (n == 0) {
                    if (k < HH)       val = Wlin[k];
                    else if (k == 51) val = blin[0];
                }
            }
            val *= sc;
            _Float16 hi = (_Float16)val;
            unsigned short bits;
            if (hl) { float lo = val - (float)hi; bits = f2h_bits(lo); }
            else    { bits = __builtin_bit_cast(unsigned short, hi); }
            packed |= ((unsigned int)bits) << (16 * e);
        }
        dw[d] = packed;
    }
    frags[f * 64 + lane] = make_uint4(dw[0], dw[1], dw[2], dw[3]);
}

// -------------------------------------------------------------------------
// MERGED-CELL kernel: 4 waves (256 thr), one wave per SIMD, each wave owns
// 16 u-columns of BOTH cells (+ rotated head).
//   iter n: cell1: h1(n)   = f(h1(n-1))            [n < TT]
//           cell2: h2(n-1) = f(h1(n-1), h2(n-2))   [1 <= n <= TT]
//           head : out(n-2) from h2(n-2)           [2 <= n <= TT+1, w==n&3]
//   Both cells read the SAME a0/a1 (h1(n-1)); head reuses a2/a3 (h2(n-2)).
// Rationale (r1/r2 post-mortem): with 1 c1-wave + 1 c2-wave per SIMD the
// dependency handoff phase-locks MFMA-burst/trans-burst across waves ->
// matrix and VALU pipes serialize (930 + ~1000 cy/step ~= measured 3100).
// Merging gives each in-order wave independent MFMA + VALU streams so the
// two pipes overlap via ILP. Ping-pong buffers, ONE barrier per iter.
// Weights stay in AGPRs (unified file, 52 frags = 208 regs, 1 wave/SIMD
// budget 512). No pins (r2: pins cost 20us, weights were already resident).
// -------------------------------------------------------------------------
__launch_bounds__(256, 1)
__global__ void lstm_main(const float* __restrict__ input,
                          const uint4* __restrict__ frags,
                          float* __restrict__ out) {
    __shared__ __align__(16) unsigned int h1[2][16][36];
    __shared__ __align__(16) unsigned int h2[2][16][36];
    __shared__ __align__(16) float xb[(TT + 1) * 16];    // [t][b], row TT = 0

    const int tid  = threadIdx.x;
    const int lane = tid & 63;
    const int w    = tid >> 6;        // 0..3 == U (u-column group)
    const int l15  = lane & 15;
    const int q    = lane >> 4;
    const int b0g  = blockIdx.x * NB;
    const int uc   = w * 16 + l15;
    const bool uok = (uc < HH);

    for (int i = tid; i < 2 * 16 * 36; i += 256) {
        ((unsigned*)h1)[i] = 0; ((unsigned*)h2)[i] = 0;
    }
    for (int c = 0; c < 4; c++) {
        int flat = tid + c * 256;
        int b = flat >> 6, t0 = (flat & 63) * 4;
        float4 v = *(const float4*)&input[(size_t)(b0g + b) * TT + t0];
        xb[(t0 + 0) * 16 + b] = v.x; xb[(t0 + 1) * 16 + b] = v.y;
        xb[(t0 + 2) * 16 + b] = v.z; xb[(t0 + 3) * 16 + b] = v.w;
    }
    if (tid < 16) xb[TT * 16 + tid] = 0.f;
    __syncthreads();
    if (tid < 16) {                         // initial hooks: h1(-1) = buffer 1
        int b = tid;
        int wi51 = ((25 + 4 * (b >> 1)) & 31) * 2 + 1;   // u=51 (bias col)
        int wi52 = ((26 + 4 * (b >> 1)) & 31) * 2 + 0;   // u=52 (x_hi)
        int wi53 = ((26 + 4 * (b >> 1)) & 31) * 2 + 1;   // u=53 (x_lo)
        ((unsigned short*)&h1[1][b][0])[wi51] = 0x3C00;  // fp16(1.0)
        float x0 = input[(size_t)(b0g + b) * TT];
        _Float16 xh = (_Float16)x0;
        ((unsigned short*)&h1[1][b][0])[wi52] = __builtin_bit_cast(unsigned short, xh);
        ((unsigned short*)&h1[1][b][0])[wi53] = f2h_bits(x0 - (float)xh);
    }

    // weight-stationary fragments: cell1 (16) + cell2 (32) + head (4)
    half8 fr1[16], fr2[32], frh[4];
#pragma unroll
    for (int g = 0; g < 4; g++) {
        int tau = g * 4 + w;
#pragma unroll
        for (int s = 0; s < 2; s++) {
            fr1[g * 4 + s * 2 + 0] = __builtin_bit_cast(half8, frags[((tau * 2 + s) * 2 + 0) * 64 + lane]);
            fr1[g * 4 + s * 2 + 1] = __builtin_bit_cast(half8, frags[((tau * 2 + s) * 2 + 1) * 64 + lane]);
        }
#pragma unroll
        for (int s = 0; s < 4; s++) {
            fr2[g * 8 + s * 2 + 0] = __builtin_bit_cast(half8, frags[(64 + (tau * 4 + s) * 2 + 0) * 64 + lane]);
            fr2[g * 8 + s * 2 + 1] = __builtin_bit_cast(half8, frags[(64 + (tau * 4 + s) * 2 + 1) * 64 + lane]);
        }
    }
#pragma unroll
    for (int s = 0; s < 2; s++) {
        frh[s * 2 + 0] = __builtin_bit_cast(half8, frags[(192 + s * 2 + 0) * 64 + lane]);
        frh[s * 2 + 1] = __builtin_bit_cast(half8, frags[(192 + s * 2 + 1) * 64 + lane]);
    }

    floatx4 zacc = {0.f, 0.f, 0.f, 0.f};
    float cst1[4] = {0.f, 0.f, 0.f, 0.f};
    float cst2[4] = {0.f, 0.f, 0.f, 0.f};
    const int baseA = (q * 4 + 4 * (l15 >> 1)) & 31;
    const int baseB = (baseA + 16) & 31;

    __syncthreads();

#define GTAIL(DG, FG, SGN)                                                      \
    _Pragma("unroll")                                                           \
    for (int r = 0; r < 4; r++) {                                               \
        float e = exp2_fast(SGN (DG)[r]);                                       \
        (FG)[r] = rcp_fast(1.0f + e);                                           \
    }

#define ITER(N, P)                                                              \
    do {                                                                        \
        const bool do1 = (N) < TT;                                              \
        const bool do2 = ((N) >= 1) && ((N) <= TT);                             \
        const bool doH = ((N) >= 2) && ((N) <= TT + 1) && (w == ((N) & 3));     \
        const unsigned int* p1r = &h1[1 - (P)][l15][0];   /* h1(n-1) */         \
        half8 a0 = *(const half8*)(p1r + baseA);                                \
        half8 a1 = *(const half8*)(p1r + baseB);                                \
        half8 a2, a3;                                                           \
        if ((N) >= 1) {                                                         \
            const unsigned int* p2r = &h2[(P)][l15][0];   /* h2(n-2) */         \
            a2 = *(const half8*)(p2r + baseA);                                  \
            a3 = *(const half8*)(p2r + baseB);                                  \
        }                                                                       \
        floatx4 d0, d1, d2, d3;                                                 \
        if (do1) {                              /* cell1 gates (16 MFMA) */     \
            d0 = MFMA16F(a0, fr1[0],  zacc); d0 = MFMA16F(a0, fr1[1],  d0);     \
            d1 = MFMA16F(a0, fr1[4],  zacc); d1 = MFMA16F(a0, fr1[5],  d1);     \
            d2 = MFMA16F(a0, fr1[8],  zacc); d2 = MFMA16F(a0, fr1[9],  d2);     \
            d3 = MFMA16F(a0, fr1[12], zacc); d3 = MFMA16F(a0, fr1[13], d3);     \
            d0 = MFMA16F(a1, fr1[2],  d0);   d0 = MFMA16F(a1, fr1[3],  d0);     \
            d1 = MFMA16F(a1, fr1[6],  d1);   d1 = MFMA16F(a1, fr1[7],  d1);     \
            d2 = MFMA16F(a1, fr1[10], d2);   d2 = MFMA16F(a1, fr1[11], d2);     \
            d3 = MFMA16F(a1, fr1[14], d3);   d3 = MFMA16F(a1, fr1[15], d3);     \
        }                                                                       \
        floatx4 e0, e1, e2, e3, ho;                                             \
        if (do2) {                              /* cell2 gates (32 MFMA) */     \
            e0 = MFMA16F(a0, fr2[0],  zacc); e0 = MFMA16F(a0, fr2[1],  e0);     \
            e1 = MFMA16F(a0, fr2[8],  zacc); e1 = MFMA16F(a0, fr2[9],  e1);     \
            e2 = MFMA16F(a0, fr2[16], zacc); e2 = MFMA16F(a0, fr2[17], e2);     \
            e3 = MFMA16F(a0, fr2[24], zacc); e3 = MFMA16F(a0, fr2[25], e3);     \
            e0 = MFMA16F(a1, fr2[2],  e0);   e0 = MFMA16F(a1, fr2[3],  e0);     \
            e1 = MFMA16F(a1, fr2[10], e1);   e1 = MFMA16F(a1, fr2[11], e1);     \
            e2 = MFMA16F(a1, fr2[18], e2);   e2 = MFMA16F(a1, fr2[19], e2);     \
            e3 = MFMA16F(a1, fr2[26], e3);   e3 = MFMA16F(a1, fr2[27], e3);     \
            e0 = MFMA16F(a2, fr2[4],  e0);   e0 = MFMA16F(a2, fr2[5],  e0);     \
            e1 = MFMA16F(a2, fr2[12], e1);   e1 = MFMA16F(a2, fr2[13], e1);     \
            e2 = MFMA16F(a2, fr2[20], e2);   e2 = MFMA16F(a2, fr2[21], e2);     \
            e3 = MFMA16F(a2, fr2[28], e3);   e3 = MFMA16F(a2, fr2[29], e3);     \
            e0 = MFMA16F(a3, fr2[6],  e0);   e0 = MFMA16F(a3, fr2[7],  e0);     \
            e1 = MFMA16F(a3, fr2[14], e1);   e1 = MFMA16F(a3, fr2[15], e1);     \
            e2 = MFMA16F(a3, fr2[22], e2);   e2 = MFMA16F(a3, fr2[23], e2);     \
            e3 = MFMA16F(a3, fr2[30], e3);   e3 = MFMA16F(a3, fr2[31], e3);     \
        }                                                                       \
        if (doH) {                              /* head (4 MFMA, reuses a2/a3) */ \
            ho = MFMA16F(a2, frh[0], zacc); ho = MFMA16F(a2, frh[1], ho);       \
            ho = MFMA16F(a3, frh[2], ho);   ho = MFMA16F(a3, frh[3], ho);       \
        }                                                                       \
        if (do1) {                              /* cell1 tail -> h1(n) */       \
            float4 xn = {0.f, 0.f, 0.f, 0.f};                                   \
            if (uc >= HH) xn = *(const float4*)&xb[((N) + 1) * 16 + q * 4];     \
            floatx4 f0, f1, f2, f3;                                             \
            GTAIL(d0, f0, -) GTAIL(d1, f1, -) GTAIL(d2, f2, +) GTAIL(d3, f3, -) \
            _Pragma("unroll")                                                   \
            for (int r = 0; r < 4; r++) {                                       \
                float tgs = fmaf(-4.0f * L2E, f2[r], 2.0f * L2E);               \
                float cn  = fmaf(f1[r], cst1[r], f0[r] * tgs);                  \
                cst1[r] = cn;                                                   \
                float th = fmaf(-2.0f, rcp_fast(1.0f + exp2_fast(cn)), 1.0f);   \
                float hv = f3[r] * th;                                          \
                hv = uok ? hv                                                   \
                         : (uc == 51 ? 1.0f                                     \
                         : (uc == 52 ? xn[r]                                    \
                         : (uc == 53 ? xn[r] - (float)(_Float16)xn[r] : 0.f))); \
                int bb = q * 4 + r;                                             \
                int wi = (((uc >> 1) + 4 * (bb >> 1)) & 31) * 2 + (uc & 1);     \
                ((unsigned short*)&h1[(P)][bb][0])[wi] = f2h_bits(hv);          \
            }                                                                   \
        }                                                                       \
        if (do2) {                              /* cell2 tail -> h2(n-1) */     \
            floatx4 f0, f1, f2, f3;                                             \
            GTAIL(e0, f0, -) GTAIL(e1, f1, -) GTAIL(e2, f2, +) GTAIL(e3, f3, -) \
            _Pragma("unroll")                                                   \
            for (int r = 0; r < 4; r++) {                                       \
                float tgs = fmaf(-4.0f * L2E, f2[r], 2.0f * L2E);               \
                float cn  = fmaf(f1[r], cst2[r], f0[r] * tgs);                  \
                cst2[r] = cn;                                                   \
                float th = fmaf(-2.0f, rcp_fast(1.0f + exp2_fast(cn)), 1.0f);   \
                float hv = f3[r] * th;                                          \
                hv = uok ? hv : (uc == 51 ? 1.0f : 0.f);                        \
                int bb = q * 4 + r;                                             \
                int wi = (((uc >> 1) + 4 * (bb >> 1)) & 31) * 2 + (uc & 1);     \
                ((unsigned short*)&h2[1 - (P)][bb][0])[wi] = f2h_bits(hv);      \
            }                                                                   \
        }                                                                       \
        if (doH && l15 == 0) {                                                  \
            _Pragma("unroll")                                                   \
            for (int r = 0; r < 4; r++)                                         \
                out[(size_t)(b0g + q * 4 + r) * TT + ((N) - 2)] = ho[r];        \
        }                                                                       \
        __syncthreads();                                                        \
    } while (0)

#pragma unroll 1
    for (int n0 = 0; n0 < TT + 2; n0 += 2) {   // n = 0..257
        ITER(n0, 0);
        ITER(n0 + 1, 1);
    }
#undef ITER
#undef GTAIL
}

extern "C" void kernel_launch(void* const* d_in, const int* in_sizes, int n_in,
                              void* d_out, int out_size, void* d_ws, size_t ws_size,
                              hipStream_t stream) {
    const float* input = (const float*)d_in[0];
    const float* Wih1  = (const float*)d_in[1];
    const float* Whh1  = (const float*)d_in[2];
    const float* bih1  = (const float*)d_in[3];
    const float* bhh1  = (const float*)d_in[4];
    const float* Wih2  = (const float*)d_in[5];
    const float* Whh2  = (const float*)d_in[6];
    const float* bih2  = (const float*)d_in[7];
    const float* bhh2  = (const float*)d_in[8];
    const float* Wlin  = (const float*)d_in[9];
    const float* blin  = (const float*)d_in[10];

    uint4* frags = (uint4*)d_ws;            // 196 frags * 1 KiB
    int B = in_sizes[0] / TT;               // 4096

    lstm_prep<<<49, 256, 0, stream>>>(Whh1, Wih1, bih1, bhh1, Wih2, Whh2,
                                      bih2, bhh2, Wlin, blin, frags);
    lstm_main<<<B / NB, 256, 0, stream>>>(input, frags, (float*)d_out);
}

// Round 4
// 385.980 us; speedup vs baseline: 1.2078x; 1.2078x over previous
//
#include <hip/hip_runtime.h>

#define HH 51
#define TT 256
#define NB 16
#define L2E 1.442695041f

typedef __attribute__((ext_vector_type(8))) _Float16 half8;
typedef __attribute__((ext_vector_type(4))) float   floatx4;

#define MFMA16F(A,B,C) __builtin_amdgcn_mfma_f32_16x16x32_f16((A),(B),(C),0,0,0)

__device__ __forceinline__ float rcp_fast(float x) { return __builtin_amdgcn_rcpf(x); }
#if __has_builtin(__builtin_amdgcn_exp2f)
__device__ __forceinline__ float exp2_fast(float x) { return __builtin_amdgcn_exp2f(x); }
#else
__device__ __forceinline__ float exp2_fast(float x) { return __expf(0.69314718056f * x); }
#endif
__device__ __forceinline__ unsigned short f2h_bits(float v) {
    return __builtin_bit_cast(unsigned short, (_Float16)v);
}

// ------------- weight pre-pack: fp16 hi/lo fragments, K-column folding ---
// (UNCHANGED from the 377us version; layout comments there still apply.)
__global__ void lstm_prep(const float* __restrict__ Whh1, const float* __restrict__ Wih1,
                          const float* __restrict__ bih1, const float* __restrict__ bhh1,
                          const float* __restrict__ Wih2, const float* __restrict__ Whh2,
                          const float* __restrict__ bih2, const float* __restrict__ bhh2,
                          const float* __restrict__ Wlin, const float* __restrict__ blin,
                          uint4* __restrict__ frags) {
    int tid = blockIdx.x * blockDim.x + threadIdx.x;
    if (tid >= 196 * 64) return;
    int f = tid >> 6, lane = tid & 63;
    int n = lane & 15, qq = lane >> 4;
    int hl, s, tau, cell;
    if (f < 64)       { cell = 1; int r = f;       hl = r & 1; r >>= 1; s = r & 1; tau = r >> 1; }
    else if (f < 192) { cell = 2; int r = f - 64;  hl = r & 1; r >>= 1; s = r & 3; tau = r >> 2; }
    else              { cell = 3; int r = f - 192; hl = r & 1; s = r >> 1; tau = 0; }
    int g = tau >> 2, U = tau & 3, u = U * 16 + n;
    float sc = (cell == 3) ? 1.0f : ((g == 2) ? 2.0f * L2E : L2E);
    unsigned int dw[4];
    for (int d = 0; d < 4; d++) {
        unsigned int packed = 0;
        for (int e = 0; e < 2; e++) {
            int jj = d * 2 + e;
            int k = s * 32 + qq * 8 + jj;
            float val = 0.f;
            if (cell == 1) {
                if (u < HH) {
                    if (k < HH)       val = Whh1[(g * HH + u) * HH + k];
                    else if (k == 51) val = bih1[g * HH + u] + bhh1[g * HH + u];
                    else              val = Wih1[g * HH + u];   // k=52,53
                }
            } else if (cell == 2) {
                if (u < HH) {
                    if (k < 64) {
                        if (k < HH)       val = Wih2[(g * HH + u) * HH + k];
                        else if (k == 51) val = bih2[g * HH + u] + bhh2[g * HH + u];
                        // k=52,53 stay 0 (x pass-through)
                    } else {
                        int k2 = k - 64;
                        if (k2 < HH) val = Whh2[(g * HH + u) * HH + k2];
                    }
                }
            } else {
                if (n == 0) {
                    if (k < HH)       val = Wlin[k];
                    else if (k == 51) val = blin[0];
                }
            }
            val *= sc;
            _Float16 hi = (_Float16)val;
            unsigned short bits;
            if (hl) { float lo = val - (float)hi; bits = f2h_bits(lo); }
            else    { bits = __builtin_bit_cast(unsigned short, hi); }
            packed |= ((unsigned int)bits) << (16 * e);
        }
        dw[d] = packed;
    }
    frags[f * 64 + lane] = make_uint4(dw[0], dw[1], dw[2], dw[3]);
}

// -------------------------------------------------------------------------
// ANTI-PHASE kernel (r3 post-mortem): 8 waves as in the 335us baseline, but
// each timestep is TWO barrier intervals with statically opposite roles:
//   A(k): c1 waves: VALU tail of gates(k-1) -> write h1(k-1)
//         c2 waves: MFMA for h2(k-2)  (reads h1(k-2), h2(k-3))
//   B(k): c1 waves: MFMA gates(k) (reads h1(k-1)) + rotated head (h2(k-3))
//         c2 waves: VALU tail -> write h2(k-2)
// Every interval = one wave/SIMD on matrix pipe + one on VALU pipe --
// overlap enforced by construction (r0/r1 showed phase-lock makes the pipes
// serialize; r3 showed 1-wave ILP exposes latency). Accumulators persist
// across one barrier. Ring depth 4; all slots disjoint per interval.
// Op order per output value is verbatim from the baseline -> bit-identical.
// -------------------------------------------------------------------------
__launch_bounds__(512, 2)
__global__ void lstm_main(const float* __restrict__ input,
                          const uint4* __restrict__ frags,
                          float* __restrict__ out) {
    __shared__ __align__(16) unsigned int h1r[4][16][36];
    __shared__ __align__(16) unsigned int h2r[4][16][36];
    __shared__ __align__(16) float xb[(TT + 1) * 16];    // [t][b], row TT = 0

    const int tid  = threadIdx.x;
    const int lane = tid & 63;
    const int w    = tid >> 6;
    const int l15  = lane & 15;
    const int q    = lane >> 4;
    const int b0g  = blockIdx.x * NB;
    const bool c2w = (w < 4);
    const int U    = c2w ? w : (w - 4);
    const int uc   = U * 16 + l15;
    const bool uok = (uc < HH);

    for (int i = tid; i < 4 * 16 * 36; i += 512) {
        ((unsigned*)h1r)[i] = 0; ((unsigned*)h2r)[i] = 0;
    }
    for (int c = 0; c < 2; c++) {
        int flat = tid + c * 512;
        int b = flat >> 6, t0 = (flat & 63) * 4;
        float4 v = *(const float4*)&input[(size_t)(b0g + b) * TT + t0];
        xb[(t0 + 0) * 16 + b] = v.x; xb[(t0 + 1) * 16 + b] = v.y;
        xb[(t0 + 2) * 16 + b] = v.z; xb[(t0 + 3) * 16 + b] = v.w;
    }
    if (tid < 16) xb[TT * 16 + tid] = 0.f;
    __syncthreads();
    if (tid < 16) {                         // initial hooks: h1(-1) = ring slot 3
        int b = tid;
        int wi51 = ((25 + 4 * (b >> 1)) & 31) * 2 + 1;   // u=51 (bias col)
        int wi52 = ((26 + 4 * (b >> 1)) & 31) * 2 + 0;   // u=52 (x_hi)
        int wi53 = ((26 + 4 * (b >> 1)) & 31) * 2 + 1;   // u=53 (x_lo)
        ((unsigned short*)&h1r[3][b][0])[wi51] = 0x3C00;  // fp16(1.0)
        float x0 = input[(size_t)(b0g + b) * TT];
        _Float16 xh = (_Float16)x0;
        ((unsigned short*)&h1r[3][b][0])[wi52] = __builtin_bit_cast(unsigned short, xh);
        ((unsigned short*)&h1r[3][b][0])[wi53] = f2h_bits(x0 - (float)xh);
    }

    // weight-stationary fragments (identical to baseline)
    half8 fr[32];
    if (c2w) {
#pragma unroll
        for (int g = 0; g < 4; g++) {
            int tau = g * 4 + U;
#pragma unroll
            for (int s = 0; s < 4; s++) {
                fr[g * 8 + s * 2 + 0] = __builtin_bit_cast(half8, frags[(64 + (tau * 4 + s) * 2 + 0) * 64 + lane]);
                fr[g * 8 + s * 2 + 1] = __builtin_bit_cast(half8, frags[(64 + (tau * 4 + s) * 2 + 1) * 64 + lane]);
            }
        }
    } else {
#pragma unroll
        for (int g = 0; g < 4; g++) {
            int tau = g * 4 + U;
#pragma unroll
            for (int s = 0; s < 2; s++) {
                fr[g * 4 + s * 2 + 0] = __builtin_bit_cast(half8, frags[((tau * 2 + s) * 2 + 0) * 64 + lane]);
                fr[g * 4 + s * 2 + 1] = __builtin_bit_cast(half8, frags[((tau * 2 + s) * 2 + 1) * 64 + lane]);
            }
        }
#pragma unroll
        for (int s = 0; s < 2; s++) {       // head frags on ALL c1 waves
            fr[16 + s * 2 + 0] = __builtin_bit_cast(half8, frags[(192 + s * 2 + 0) * 64 + lane]);
            fr[16 + s * 2 + 1] = __builtin_bit_cast(half8, frags[(192 + s * 2 + 1) * 64 + lane]);
        }
    }
    floatx4 zacc = {0.f, 0.f, 0.f, 0.f};
    float cst[4] = {0.f, 0.f, 0.f, 0.f};
    const int baseA = (q * 4 + 4 * (l15 >> 1)) & 31;
    const int baseB = (baseA + 16) & 31;

    // persistent gate accumulators (live across ONE barrier each step)
    floatx4 g0 = zacc, g1 = zacc, g2 = zacc, g3 = zacc;

    __syncthreads();

#define GTAIL(DG, FG, SGN)                                                      \
    _Pragma("unroll")                                                           \
    for (int r = 0; r < 4; r++) {                                               \
        float e = exp2_fast(SGN (DG)[r]);                                       \
        (FG)[r] = rcp_fast(1.0f + e);                                           \
    }

#pragma unroll 1
    for (int k = 0; k <= TT + 2; ++k) {
        // ================= interval A(k) =================
        if (c2w) {
            if (k >= 2 && k <= TT + 1) {        // MFMA for h2(k-2)
                const unsigned int* p1 = &h1r[(k - 2) & 3][l15][0];
                const unsigned int* p2 = &h2r[(k - 3) & 3][l15][0];
                half8 a0 = *(const half8*)(p1 + baseA);
                half8 a1 = *(const half8*)(p1 + baseB);
                half8 a2 = *(const half8*)(p2 + baseA);
                half8 a3 = *(const half8*)(p2 + baseB);
                g0 = MFMA16F(a0, fr[0],  zacc); g0 = MFMA16F(a0, fr[1],  g0);
                g1 = MFMA16F(a0, fr[8],  zacc); g1 = MFMA16F(a0, fr[9],  g1);
                g2 = MFMA16F(a0, fr[16], zacc); g2 = MFMA16F(a0, fr[17], g2);
                g3 = MFMA16F(a0, fr[24], zacc); g3 = MFMA16F(a0, fr[25], g3);
                g0 = MFMA16F(a1, fr[2],  g0);   g0 = MFMA16F(a1, fr[3],  g0);
                g1 = MFMA16F(a1, fr[10], g1);   g1 = MFMA16F(a1, fr[11], g1);
                g2 = MFMA16F(a1, fr[18], g2);   g2 = MFMA16F(a1, fr[19], g2);
                g3 = MFMA16F(a1, fr[26], g3);   g3 = MFMA16F(a1, fr[27], g3);
                g0 = MFMA16F(a2, fr[4],  g0);   g0 = MFMA16F(a2, fr[5],  g0);
                g1 = MFMA16F(a2, fr[12], g1);   g1 = MFMA16F(a2, fr[13], g1);
                g2 = MFMA16F(a2, fr[20], g2);   g2 = MFMA16F(a2, fr[21], g2);
                g3 = MFMA16F(a2, fr[28], g3);   g3 = MFMA16F(a2, fr[29], g3);
                g0 = MFMA16F(a3, fr[6],  g0);   g0 = MFMA16F(a3, fr[7],  g0);
                g1 = MFMA16F(a3, fr[14], g1);   g1 = MFMA16F(a3, fr[15], g1);
                g2 = MFMA16F(a3, fr[22], g2);   g2 = MFMA16F(a3, fr[23], g2);
                g3 = MFMA16F(a3, fr[30], g3);   g3 = MFMA16F(a3, fr[31], g3);
            }
        } else {
            if (k >= 1 && k <= TT) {            // tail of gates(k-1) -> h1(k-1)
                const int j = k - 1;
                float4 xn = {0.f, 0.f, 0.f, 0.f};
                if (uc >= HH) xn = *(const float4*)&xb[(j + 1) * 16 + q * 4];
                floatx4 f0, f1, f2, f3;
                GTAIL(g0, f0, -) GTAIL(g1, f1, -) GTAIL(g2, f2, +) GTAIL(g3, f3, -)
#pragma unroll
                for (int r = 0; r < 4; r++) {
                    float tgs = fmaf(-4.0f * L2E, f2[r], 2.0f * L2E);
                    float cn  = fmaf(f1[r], cst[r], f0[r] * tgs);
                    cst[r] = cn;
                    float th = fmaf(-2.0f, rcp_fast(1.0f + exp2_fast(cn)), 1.0f);
                    float hv = f3[r] * th;
                    hv = uok ? hv
                             : (uc == 51 ? 1.0f
                             : (uc == 52 ? xn[r]
                             : (uc == 53 ? xn[r] - (float)(_Float16)xn[r] : 0.f)));
                    int bb = q * 4 + r;
                    int wi = (((uc >> 1) + 4 * (bb >> 1)) & 31) * 2 + (uc & 1);
                    ((unsigned short*)&h1r[j & 3][bb][0])[wi] = f2h_bits(hv);
                }
            }
        }
        __syncthreads();
        // ================= interval B(k) =================
        if (c2w) {
            if (k >= 2 && k <= TT + 1) {        // tail -> h2(k-2)
                floatx4 f0, f1, f2, f3;
                GTAIL(g0, f0, -) GTAIL(g1, f1, -) GTAIL(g2, f2, +) GTAIL(g3, f3, -)
#pragma unroll
                for (int r = 0; r < 4; r++) {
                    float tgs = fmaf(-4.0f * L2E, f2[r], 2.0f * L2E);
                    float cn  = fmaf(f1[r], cst[r], f0[r] * tgs);
                    cst[r] = cn;
                    float th = fmaf(-2.0f, rcp_fast(1.0f + exp2_fast(cn)), 1.0f);
                    float hv = f3[r] * th;
                    hv = uok ? hv : (uc == 51 ? 1.0f : 0.f);
                    int bb = q * 4 + r;
                    int wi = (((uc >> 1) + 4 * (bb >> 1)) & 31) * 2 + (uc & 1);
                    ((unsigned short*)&h2r[(k - 2) & 3][bb][0])[wi] = f2h_bits(hv);
                }
            }
        } else {
            if (k <= TT - 1) {                  // MFMA gates(k), reads h1(k-1)
                const unsigned int* p1 = &h1r[(k + 3) & 3][l15][0];
                half8 a0 = *(const half8*)(p1 + baseA);
                half8 a1 = *(const half8*)(p1 + baseB);
                g0 = MFMA16F(a0, fr[0],  zacc); g0 = MFMA16F(a0, fr[1],  g0);
                g1 = MFMA16F(a0, fr[4],  zacc); g1 = MFMA16F(a0, fr[5],  g1);
                g2 = MFMA16F(a0, fr[8],  zacc); g2 = MFMA16F(a0, fr[9],  g2);
                g3 = MFMA16F(a0, fr[12], zacc); g3 = MFMA16F(a0, fr[13], g3);
                g0 = MFMA16F(a1, fr[2],  g0);   g0 = MFMA16F(a1, fr[3],  g0);
                g1 = MFMA16F(a1, fr[6],  g1);   g1 = MFMA16F(a1, fr[7],  g1);
                g2 = MFMA16F(a1, fr[10], g2);   g2 = MFMA16F(a1, fr[11], g2);
                g3 = MFMA16F(a1, fr[14], g3);   g3 = MFMA16F(a1, fr[15], g3);
            }
            if (k >= 3 && (w - 4) == ((k - 3) & 3)) {   // head: out col k-3
                const unsigned int* p2 = &h2r[(k - 3) & 3][l15][0];
                half8 a2 = *(const half8*)(p2 + baseA);
                half8 a3 = *(const half8*)(p2 + baseB);
                floatx4 ho;
                ho = MFMA16F(a2, fr[16], zacc); ho = MFMA16F(a2, fr[17], ho);
                ho = MFMA16F(a3, fr[18], ho);   ho = MFMA16F(a3, fr[19], ho);
                if (l15 == 0) {
#pragma unroll
                    for (int r = 0; r < 4; r++)
                        out[(size_t)(b0g + q * 4 + r) * TT + (k - 3)] = ho[r];
                }
            }
        }
        __syncthreads();
    }
#undef GTAIL
}

extern "C" void kernel_launch(void* const* d_in, const int* in_sizes, int n_in,
                              void* d_out, int out_size, void* d_ws, size_t ws_size,
                              hipStream_t stream) {
    const float* input = (const float*)d_in[0];
    const float* Wih1  = (const float*)d_in[1];
    const float* Whh1  = (const float*)d_in[2];
    const float* bih1  = (const float*)d_in[3];
    const float* bhh1  = (const float*)d_in[4];
    const float* Wih2  = (const float*)d_in[5];
    const float* Whh2  = (const float*)d_in[6];
    const float* bih2  = (const float*)d_in[7];
    const float* bhh2  = (const float*)d_in[8];
    const float* Wlin  = (const float*)d_in[9];
    const float* blin  = (const float*)d_in[10];

    uint4* frags = (uint4*)d_ws;            // 196 frags * 1 KiB
    int B = in_sizes[0] / TT;               // 4096

    lstm_prep<<<49, 256, 0, stream>>>(Whh1, Wih1, bih1, bhh1, Wih2, Whh2,
                                      bih2, bhh2, Wlin, blin, frags);
    lstm_main<<<B / NB, 512, 0, stream>>>(input, frags, (float*)d_out);
}

// Round 5
// 385.049 us; speedup vs baseline: 1.2107x; 1.0024x over previous
//
#include <hip/hip_runtime.h>

#define HH 51
#define TT 256
#define NB 16
#define L2E 1.442695041f

typedef __attribute__((ext_vector_type(8))) _Float16 half8;
typedef __attribute__((ext_vector_type(4))) float   floatx4;

#define MFMA16F(A,B,C) __builtin_amdgcn_mfma_f32_16x16x32_f16((A),(B),(C),0,0,0)

__device__ __forceinline__ float rcp_fast(float x) { return __builtin_amdgcn_rcpf(x); }
#if __has_builtin(__builtin_amdgcn_exp2f)
__device__ __forceinline__ float exp2_fast(float x) { return __builtin_amdgcn_exp2f(x); }
#else
__device__ __forceinline__ float exp2_fast(float x) { return __expf(0.69314718056f * x); }
#endif
__device__ __forceinline__ unsigned short f2h_bits(float v) {
    return __builtin_bit_cast(unsigned short, (_Float16)v);
}

// ------------- weight pre-pack: fp16 hi/lo fragments, K-column folding ---
// (UNCHANGED from the 377us version; layout comments there still apply.)
__global__ void lstm_prep(const float* __restrict__ Whh1, const float* __restrict__ Wih1,
                          const float* __restrict__ bih1, const float* __restrict__ bhh1,
                          const float* __restrict__ Wih2, const float* __restrict__ Whh2,
                          const float* __restrict__ bih2, const float* __restrict__ bhh2,
                          const float* __restrict__ Wlin, const float* __restrict__ blin,
                          uint4* __restrict__ frags) {
    int tid = blockIdx.x * blockDim.x + threadIdx.x;
    if (tid >= 196 * 64) return;
    int f = tid >> 6, lane = tid & 63;
    int n = lane & 15, qq = lane >> 4;
    int hl, s, tau, cell;
    if (f < 64)       { cell = 1; int r = f;       hl = r & 1; r >>= 1; s = r & 1; tau = r >> 1; }
    else if (f < 192) { cell = 2; int r = f - 64;  hl = r & 1; r >>= 1; s = r & 3; tau = r >> 2; }
    else              { cell = 3; int r = f - 192; hl = r & 1; s = r >> 1; tau = 0; }
    int g = tau >> 2, U = tau & 3, u = U * 16 + n;
    float sc = (cell == 3) ? 1.0f : ((g == 2) ? 2.0f * L2E : L2E);
    unsigned int dw[4];
    for (int d = 0; d < 4; d++) {
        unsigned int packed = 0;
        for (int e = 0; e < 2; e++) {
            int jj = d * 2 + e;
            int k = s * 32 + qq * 8 + jj;
            float val = 0.f;
            if (cell == 1) {
                if (u < HH) {
                    if (k < HH)       val = Whh1[(g * HH + u) * HH + k];
                    else if (k == 51) val = bih1[g * HH + u] + bhh1[g * HH + u];
                    else              val = Wih1[g * HH + u];   // k=52,53
                }
            } else if (cell == 2) {
                if (u < HH) {
                    if (k < 64) {
                        if (k < HH)       val = Wih2[(g * HH + u) * HH + k];
                        else if (k == 51) val = bih2[g * HH + u] + bhh2[g * HH + u];
                        // k=52,53 stay 0 (x pass-through)
                    } else {
                        int k2 = k - 64;
                        if (k2 < HH) val = Whh2[(g * HH + u) * HH + k2];
                    }
                }
            } else {
                if (n == 0) {
                    if (k < HH)       val = Wlin[k];
                    else if (k == 51) val = blin[0];
                }
            }
            val *= sc;
            _Float16 hi = (_Float16)val;
            unsigned short bits;
            if (hl) { float lo = val - (float)hi; bits = f2h_bits(lo); }
            else    { bits = __builtin_bit_cast(unsigned short, hi); }
            packed |= ((unsigned int)bits) << (16 * e);
        }
        dw[d] = packed;
    }
    frags[f * 64 + lane] = make_uint4(dw[0], dw[1], dw[2], dw[3]);
}

// -------------------------------------------------------------------------
// ANTI-PHASE kernel, MAPPING-ROBUST role split (r4 post-mortem):
// Four schedules all measured ~3100 cy/step => the c1/c2 waves were never
// co-resident on one SIMD. If wave->SIMD assignment is w/2 (consecutive
// pairs) instead of w%4, the old split (c2 = w<4) puts two SAME-role,
// phase-locked waves on every SIMD -> pipes serialize in every interval,
// which explains all four null results at once (m114 proved cross-wave
// MFMA||VALU overlap works on this HW).
// Fix: role(w) = (w&1)^((w>>2)&1) differs across BOTH w^1 (pair mapping)
// and w+-4 (round-robin mapping): c2 = {0,2,5,7}, c1 = {1,3,4,6}.
// U = (2w+1)>>2 ranks both sets 0..3. Everything else identical to r4:
//   A(k): c1: VALU tail gates(k-1) -> h1(k-1) | c2: MFMA h2(k-2)
//   B(k): c1: MFMA gates(k) + rotated head    | c2: VALU tail -> h2(k-2)
// Op order per output value verbatim -> bit-identical absmax.
// -------------------------------------------------------------------------
__launch_bounds__(512, 2)
__global__ void lstm_main(const float* __restrict__ input,
                          const uint4* __restrict__ frags,
                          float* __restrict__ out) {
    __shared__ __align__(16) unsigned int h1r[4][16][36];
    __shared__ __align__(16) unsigned int h2r[4][16][36];
    __shared__ __align__(16) float xb[(TT + 1) * 16];    // [t][b], row TT = 0

    const int tid  = threadIdx.x;
    const int lane = tid & 63;
    const int w    = tid >> 6;
    const int l15  = lane & 15;
    const int q    = lane >> 4;
    const int b0g  = blockIdx.x * NB;
    const bool c2w = (((w & 1) ^ ((w >> 2) & 1)) == 0);   // {0,2,5,7}
    const int U    = (2 * w + 1) >> 2;                    // rank 0..3 in each set
    const int uc   = U * 16 + l15;
    const bool uok = (uc < HH);

    for (int i = tid; i < 4 * 16 * 36; i += 512) {
        ((unsigned*)h1r)[i] = 0; ((unsigned*)h2r)[i] = 0;
    }
    for (int c = 0; c < 2; c++) {
        int flat = tid + c * 512;
        int b = flat >> 6, t0 = (flat & 63) * 4;
        float4 v = *(const float4*)&input[(size_t)(b0g + b) * TT + t0];
        xb[(t0 + 0) * 16 + b] = v.x; xb[(t0 + 1) * 16 + b] = v.y;
        xb[(t0 + 2) * 16 + b] = v.z; xb[(t0 + 3) * 16 + b] = v.w;
    }
    if (tid < 16) xb[TT * 16 + tid] = 0.f;
    __syncthreads();
    if (tid < 16) {                         // initial hooks: h1(-1) = ring slot 3
        int b = tid;
        int wi51 = ((25 + 4 * (b >> 1)) & 31) * 2 + 1;   // u=51 (bias col)
        int wi52 = ((26 + 4 * (b >> 1)) & 31) * 2 + 0;   // u=52 (x_hi)
        int wi53 = ((26 + 4 * (b >> 1)) & 31) * 2 + 1;   // u=53 (x_lo)
        ((unsigned short*)&h1r[3][b][0])[wi51] = 0x3C00;  // fp16(1.0)
        float x0 = input[(size_t)(b0g + b) * TT];
        _Float16 xh = (_Float16)x0;
        ((unsigned short*)&h1r[3][b][0])[wi52] = __builtin_bit_cast(unsigned short, xh);
        ((unsigned short*)&h1r[3][b][0])[wi53] = f2h_bits(x0 - (float)xh);
    }

    // weight-stationary fragments (indexed by per-wave U; identical layout)
    half8 fr[32];
    if (c2w) {
#pragma unroll
        for (int g = 0; g < 4; g++) {
            int tau = g * 4 + U;
#pragma unroll
            for (int s = 0; s < 4; s++) {
                fr[g * 8 + s * 2 + 0] = __builtin_bit_cast(half8, frags[(64 + (tau * 4 + s) * 2 + 0) * 64 + lane]);
                fr[g * 8 + s * 2 + 1] = __builtin_bit_cast(half8, frags[(64 + (tau * 4 + s) * 2 + 1) * 64 + lane]);
            }
        }
    } else {
#pragma unroll
        for (int g = 0; g < 4; g++) {
            int tau = g * 4 + U;
#pragma unroll
            for (int s = 0; s < 2; s++) {
                fr[g * 4 + s * 2 + 0] = __builtin_bit_cast(half8, frags[((tau * 2 + s) * 2 + 0) * 64 + lane]);
                fr[g * 4 + s * 2 + 1] = __builtin_bit_cast(half8, frags[((tau * 2 + s) * 2 + 1) * 64 + lane]);
            }
        }
#pragma unroll
        for (int s = 0; s < 2; s++) {       // head frags on ALL c1 waves
            fr[16 + s * 2 + 0] = __builtin_bit_cast(half8, frags[(192 + s * 2 + 0) * 64 + lane]);
            fr[16 + s * 2 + 1] = __builtin_bit_cast(half8, frags[(192 + s * 2 + 1) * 64 + lane]);
        }
    }
    floatx4 zacc = {0.f, 0.f, 0.f, 0.f};
    float cst[4] = {0.f, 0.f, 0.f, 0.f};
    const int baseA = (q * 4 + 4 * (l15 >> 1)) & 31;
    const int baseB = (baseA + 16) & 31;

    // persistent gate accumulators (live across ONE barrier each step)
    floatx4 g0 = zacc, g1 = zacc, g2 = zacc, g3 = zacc;

    __syncthreads();

#define GTAIL(DG, FG, SGN)                                                      \
    _Pragma("unroll")                                                           \
    for (int r = 0; r < 4; r++) {                                               \
        float e = exp2_fast(SGN (DG)[r]);                                       \
        (FG)[r] = rcp_fast(1.0f + e);                                           \
    }

#pragma unroll 1
    for (int k = 0; k <= TT + 2; ++k) {
        // ================= interval A(k) =================
        if (c2w) {
            if (k >= 2 && k <= TT + 1) {        // MFMA for h2(k-2)
                const unsigned int* p1 = &h1r[(k - 2) & 3][l15][0];
                const unsigned int* p2 = &h2r[(k - 3) & 3][l15][0];
                half8 a0 = *(const half8*)(p1 + baseA);
                half8 a1 = *(const half8*)(p1 + baseB);
                half8 a2 = *(const half8*)(p2 + baseA);
                half8 a3 = *(const half8*)(p2 + baseB);
                g0 = MFMA16F(a0, fr[0],  zacc); g0 = MFMA16F(a0, fr[1],  g0);
                g1 = MFMA16F(a0, fr[8],  zacc); g1 = MFMA16F(a0, fr[9],  g1);
                g2 = MFMA16F(a0, fr[16], zacc); g2 = MFMA16F(a0, fr[17], g2);
                g3 = MFMA16F(a0, fr[24], zacc); g3 = MFMA16F(a0, fr[25], g3);
                g0 = MFMA16F(a1, fr[2],  g0);   g0 = MFMA16F(a1, fr[3],  g0);
                g1 = MFMA16F(a1, fr[10], g1);   g1 = MFMA16F(a1, fr[11], g1);
                g2 = MFMA16F(a1, fr[18], g2);   g2 = MFMA16F(a1, fr[19], g2);
                g3 = MFMA16F(a1, fr[26], g3);   g3 = MFMA16F(a1, fr[27], g3);
                g0 = MFMA16F(a2, fr[4],  g0);   g0 = MFMA16F(a2, fr[5],  g0);
                g1 = MFMA16F(a2, fr[12], g1);   g1 = MFMA16F(a2, fr[13], g1);
                g2 = MFMA16F(a2, fr[20], g2);   g2 = MFMA16F(a2, fr[21], g2);
                g3 = MFMA16F(a2, fr[28], g3);   g3 = MFMA16F(a2, fr[29], g3);
                g0 = MFMA16F(a3, fr[6],  g0);   g0 = MFMA16F(a3, fr[7],  g0);
                g1 = MFMA16F(a3, fr[14], g1);   g1 = MFMA16F(a3, fr[15], g1);
                g2 = MFMA16F(a3, fr[22], g2);   g2 = MFMA16F(a3, fr[23], g2);
                g3 = MFMA16F(a3, fr[30], g3);   g3 = MFMA16F(a3, fr[31], g3);
            }
        } else {
            if (k >= 1 && k <= TT) {            // tail of gates(k-1) -> h1(k-1)
                const int j = k - 1;
                float4 xn = {0.f, 0.f, 0.f, 0.f};
                if (uc >= HH) xn = *(const float4*)&xb[(j + 1) * 16 + q * 4];
                floatx4 f0, f1, f2, f3;
                GTAIL(g0, f0, -) GTAIL(g1, f1, -) GTAIL(g2, f2, +) GTAIL(g3, f3, -)
#pragma unroll
                for (int r = 0; r < 4; r++) {
                    float tgs = fmaf(-4.0f * L2E, f2[r], 2.0f * L2E);
                    float cn  = fmaf(f1[r], cst[r], f0[r] * tgs);
                    cst[r] = cn;
                    float th = fmaf(-2.0f, rcp_fast(1.0f + exp2_fast(cn)), 1.0f);
                    float hv = f3[r] * th;
                    hv = uok ? hv
                             : (uc == 51 ? 1.0f
                             : (uc == 52 ? xn[r]
                             : (uc == 53 ? xn[r] - (float)(_Float16)xn[r] : 0.f)));
                    int bb = q * 4 + r;
                    int wi = (((uc >> 1) + 4 * (bb >> 1)) & 31) * 2 + (uc & 1);
                    ((unsigned short*)&h1r[j & 3][bb][0])[wi] = f2h_bits(hv);
                }
            }
        }
        __syncthreads();
        // ================= interval B(k) =================
        if (c2w) {
            if (k >= 2 && k <= TT + 1) {        // tail -> h2(k-2)
                floatx4 f0, f1, f2, f3;
                GTAIL(g0, f0, -) GTAIL(g1, f1, -) GTAIL(g2, f2, +) GTAIL(g3, f3, -)
#pragma unroll
                for (int r = 0; r < 4; r++) {
                    float tgs = fmaf(-4.0f * L2E, f2[r], 2.0f * L2E);
                    float cn  = fmaf(f1[r], cst[r], f0[r] * tgs);
                    cst[r] = cn;
                    float th = fmaf(-2.0f, rcp_fast(1.0f + exp2_fast(cn)), 1.0f);
                    float hv = f3[r] * th;
                    hv = uok ? hv : (uc == 51 ? 1.0f : 0.f);
                    int bb = q * 4 + r;
                    int wi = (((uc >> 1) + 4 * (bb >> 1)) & 31) * 2 + (uc & 1);
                    ((unsigned short*)&h2r[(k - 2) & 3][bb][0])[wi] = f2h_bits(hv);
                }
            }
        } else {
            if (k <= TT - 1) {                  // MFMA gates(k), reads h1(k-1)
                const unsigned int* p1 = &h1r[(k + 3) & 3][l15][0];
                half8 a0 = *(const half8*)(p1 + baseA);
                half8 a1 = *(const half8*)(p1 + baseB);
                g0 = MFMA16F(a0, fr[0],  zacc); g0 = MFMA16F(a0, fr[1],  g0);
                g1 = MFMA16F(a0, fr[4],  zacc); g1 = MFMA16F(a0, fr[5],  g1);
                g2 = MFMA16F(a0, fr[8],  zacc); g2 = MFMA16F(a0, fr[9],  g2);
                g3 = MFMA16F(a0, fr[12], zacc); g3 = MFMA16F(a0, fr[13], g3);
                g0 = MFMA16F(a1, fr[2],  g0);   g0 = MFMA16F(a1, fr[3],  g0);
                g1 = MFMA16F(a1, fr[6],  g1);   g1 = MFMA16F(a1, fr[7],  g1);
                g2 = MFMA16F(a1, fr[10], g2);   g2 = MFMA16F(a1, fr[11], g2);
                g3 = MFMA16F(a1, fr[14], g3);   g3 = MFMA16F(a1, fr[15], g3);
            }
            if (k >= 3 && U == ((k - 3) & 3)) {         // head: out col k-3
                const unsigned int* p2 = &h2r[(k - 3) & 3][l15][0];
                half8 a2 = *(const half8*)(p2 + baseA);
                half8 a3 = *(const half8*)(p2 + baseB);
                floatx4 ho;
                ho = MFMA16F(a2, fr[16], zacc); ho = MFMA16F(a2, fr[17], ho);
                ho = MFMA16F(a3, fr[18], ho);   ho = MFMA16F(a3, fr[19], ho);
                if (l15 == 0) {
#pragma unroll
                    for (int r = 0; r < 4; r++)
                        out[(size_t)(b0g + q * 4 + r) * TT + (k - 3)] = ho[r];
                }
            }
        }
        __syncthreads();
    }
#undef GTAIL
}

extern "C" void kernel_launch(void* const* d_in, const int* in_sizes, int n_in,
                              void* d_out, int out_size, void* d_ws, size_t ws_size,
                              hipStream_t stream) {
    const float* input = (const float*)d_in[0];
    const float* Wih1  = (const float*)d_in[1];
    const float* Whh1  = (const float*)d_in[2];
    const float* bih1  = (const float*)d_in[3];
    const float* bhh1  = (const float*)d_in[4];
    const float* Wih2  = (const float*)d_in[5];
    const float* Whh2  = (const float*)d_in[6];
    const float* bih2  = (const float*)d_in[7];
    const float* bhh2  = (const float*)d_in[8];
    const float* Wlin  = (const float*)d_in[9];
    const float* blin  = (const float*)d_in[10];

    uint4* frags = (uint4*)d_ws;            // 196 frags * 1 KiB
    int B = in_sizes[0] / TT;               // 4096

    lstm_prep<<<49, 256, 0, stream>>>(Whh1, Wih1, bih1, bhh1, Wih2, Whh2,
                                      bih2, bhh2, Wlin, blin, frags);
    lstm_main<<<B / NB, 512, 0, stream>>>(input, frags, (float*)d_out);
}

// Round 6
// 332.212 us; speedup vs baseline: 1.4033x; 1.1590x over previous
//
#include <hip/hip_runtime.h>

#define HH 51
#define TT 256
#define NB 16
#define L2E 1.442695041f

typedef __attribute__((ext_vector_type(8))) _Float16 half8;
typedef __attribute__((ext_vector_type(4))) float   floatx4;

#define MFMA16F(A,B,C) __builtin_amdgcn_mfma_f32_16x16x32_f16((A),(B),(C),0,0,0)

__device__ __forceinline__ float rcp_fast(float x) { return __builtin_amdgcn_rcpf(x); }
#if __has_builtin(__builtin_amdgcn_exp2f)
__device__ __forceinline__ float exp2_fast(float x) { return __builtin_amdgcn_exp2f(x); }
#else
__device__ __forceinline__ float exp2_fast(float x) { return __expf(0.69314718056f * x); }
#endif
__device__ __forceinline__ unsigned short f2h_bits(float v) {
    return __builtin_bit_cast(unsigned short, (_Float16)v);
}

// ------------- weight pre-pack: fp16 hi/lo fragments, K-column folding ---
// (UNCHANGED from the 377us version. Main kernel now loads ONLY the hi
//  fragments (hl=0); lo frags still produced but unused.)
__global__ void lstm_prep(const float* __restrict__ Whh1, const float* __restrict__ Wih1,
                          const float* __restrict__ bih1, const float* __restrict__ bhh1,
                          const float* __restrict__ Wih2, const float* __restrict__ Whh2,
                          const float* __restrict__ bih2, const float* __restrict__ bhh2,
                          const float* __restrict__ Wlin, const float* __restrict__ blin,
                          uint4* __restrict__ frags) {
    int tid = blockIdx.x * blockDim.x + threadIdx.x;
    if (tid >= 196 * 64) return;
    int f = tid >> 6, lane = tid & 63;
    int n = lane & 15, qq = lane >> 4;
    int hl, s, tau, cell;
    if (f < 64)       { cell = 1; int r = f;       hl = r & 1; r >>= 1; s = r & 1; tau = r >> 1; }
    else if (f < 192) { cell = 2; int r = f - 64;  hl = r & 1; r >>= 1; s = r & 3; tau = r >> 2; }
    else              { cell = 3; int r = f - 192; hl = r & 1; s = r >> 1; tau = 0; }
    int g = tau >> 2, U = tau & 3, u = U * 16 + n;
    float sc = (cell == 3) ? 1.0f : ((g == 2) ? 2.0f * L2E : L2E);
    unsigned int dw[4];
    for (int d = 0; d < 4; d++) {
        unsigned int packed = 0;
        for (int e = 0; e < 2; e++) {
            int jj = d * 2 + e;
            int k = s * 32 + qq * 8 + jj;
            float val = 0.f;
            if (cell == 1) {
                if (u < HH) {
                    if (k < HH)       val = Whh1[(g * HH + u) * HH + k];
                    else if (k == 51) val = bih1[g * HH + u] + bhh1[g * HH + u];
                    else              val = Wih1[g * HH + u];   // k=52,53
                }
            } else if (cell == 2) {
                if (u < HH) {
                    if (k < 64) {
                        if (k < HH)       val = Wih2[(g * HH + u) * HH + k];
                        else if (k == 51) val = bih2[g * HH + u] + bhh2[g * HH + u];
                        // k=52,53 stay 0 (x pass-through)
                    } else {
                        int k2 = k - 64;
                        if (k2 < HH) val = Whh2[(g * HH + u) * HH + k2];
                    }
                }
            } else {
                if (n == 0) {
                    if (k < HH)       val = Wlin[k];
                    else if (k == 51) val = blin[0];
                }
            }
            val *= sc;
            _Float16 hi = (_Float16)val;
            unsigned short bits;
            if (hl) { float lo = val - (float)hi; bits = f2h_bits(lo); }
            else    { bits = __builtin_bit_cast(unsigned short, hi); }
            packed |= ((unsigned int)bits) << (16 * e);
        }
        dw[d] = packed;
    }
    frags[f * 64 + lane] = make_uint4(dw[0], dw[1], dw[2], dw[3]);
}

// -------------------------------------------------------------------------
// One-barrier skewed LSTM (R0 335.7us structure), SINGLE-fp16 weights:
// r0-r5 post-mortem: six schedule variants all land at ~3150 cy/step ->
// per-SIMD work is SERIAL (CDNA4 MFMA executes on the shared SIMD datapath;
// MFMA||VALU overlap only exists ACROSS SIMDs, m114). Additive model:
// MFMA ~1000 + trans ~640 + VALU ~700 + LDS/barrier ~800 = measured.
// => only lever is total work. Largest reducible term: the hi/lo weight
// split doubled every MFMA while absmax (2^-12) is set by fp16-h storage,
// not weight precision. This version loads only hi frags:
//   c1 16->8 MFMA, c2 32->16, head 4->2  (MFMA cycles halved)
// x keeps FULL precision (x_hi/x_lo K-columns 52/53 live in the hi frag).
// Numerics: weight/bias now single-RNE-fp16 -> absmax expected ~3-8e-4.
// Everything else byte-identical to the R0 baseline.
// -------------------------------------------------------------------------
__launch_bounds__(512, 2)
__global__ void lstm_main(const float* __restrict__ input,
                          const uint4* __restrict__ frags,
                          float* __restrict__ out) {
    __shared__ __align__(16) unsigned int h1[2][16][36];
    __shared__ __align__(16) unsigned int h2[2][16][36];
    __shared__ __align__(16) float xb[(TT + 1) * 16];    // [t][b], row TT = 0

    const int tid  = threadIdx.x;
    const int lane = tid & 63;
    const int w    = tid >> 6;
    const int l15  = lane & 15;
    const int q    = lane >> 4;
    const int b0g  = blockIdx.x * NB;
    const bool c2w = (w < 4);
    const int U    = c2w ? w : (w - 4);
    const int uc   = U * 16 + l15;
    const bool uok = (uc < HH);

    for (int i = tid; i < 2 * 16 * 36; i += 512) {
        ((unsigned*)h1)[i] = 0; ((unsigned*)h2)[i] = 0;
    }
    for (int c = 0; c < 2; c++) {
        int flat = tid + c * 512;
        int b = flat >> 6, t0 = (flat & 63) * 4;
        float4 v = *(const float4*)&input[(size_t)(b0g + b) * TT + t0];
        xb[(t0 + 0) * 16 + b] = v.x; xb[(t0 + 1) * 16 + b] = v.y;
        xb[(t0 + 2) * 16 + b] = v.z; xb[(t0 + 3) * 16 + b] = v.w;
    }
    if (tid < 16) xb[TT * 16 + tid] = 0.f;
    __syncthreads();
    if (tid < 16) {                         // initial hooks in h1 parity 1
        int b = tid;
        int wi51 = ((25 + 4 * (b >> 1)) & 31) * 2 + 1;   // u=51 (bias col)
        int wi52 = ((26 + 4 * (b >> 1)) & 31) * 2 + 0;   // u=52 (x_hi)
        int wi53 = ((26 + 4 * (b >> 1)) & 31) * 2 + 1;   // u=53 (x_lo)
        ((unsigned short*)&h1[1][b][0])[wi51] = 0x3C00;  // fp16(1.0)
        float x0 = input[(size_t)(b0g + b) * TT];
        _Float16 xh = (_Float16)x0;
        ((unsigned short*)&h1[1][b][0])[wi52] = __builtin_bit_cast(unsigned short, xh);
        ((unsigned short*)&h1[1][b][0])[wi53] = f2h_bits(x0 - (float)xh);
    }

    // weight-stationary fragments -- HI ONLY (frag ids with hl=0)
    // c2 wave: fr[g*4+s], s=0..3  (16 frags)
    // c1 wave: fr[g*2+s], s=0..1  (8 frags) ; head in fr[8],fr[9]
    half8 fr[16];
    if (c2w) {
#pragma unroll
        for (int g = 0; g < 4; g++) {
            int tau = g * 4 + U;
#pragma unroll
            for (int s = 0; s < 4; s++)
                fr[g * 4 + s] = __builtin_bit_cast(half8, frags[(64 + (tau * 4 + s) * 2) * 64 + lane]);
        }
    } else {
#pragma unroll
        for (int g = 0; g < 4; g++) {
            int tau = g * 4 + U;
#pragma unroll
            for (int s = 0; s < 2; s++)
                fr[g * 2 + s] = __builtin_bit_cast(half8, frags[((tau * 2 + s) * 2) * 64 + lane]);
        }
#pragma unroll
        for (int s = 0; s < 2; s++)         // head frags on ALL c1 waves
            fr[8 + s] = __builtin_bit_cast(half8, frags[(192 + s * 2) * 64 + lane]);
    }
    floatx4 zacc = {0.f, 0.f, 0.f, 0.f};
    float cst[4] = {0.f, 0.f, 0.f, 0.f};
    const int baseA = (q * 4 + 4 * (l15 >> 1)) & 31;
    const int baseB = (baseA + 16) & 31;

    __syncthreads();

#define GTAIL(DG, FG, SGN)                                                      \
    _Pragma("unroll")                                                           \
    for (int r = 0; r < 4; r++) {                                               \
        float e = exp2_fast(SGN (DG)[r]);                                       \
        (FG)[r] = rcp_fast(1.0f + e);                                           \
    }

#define STEP(IT, P)                                                             \
    do {                                                                        \
        if (c2w) {                                                              \
            if ((IT) >= 1 && (IT) <= TT) {       /* cell2 -> h2(IT-1) */        \
                half8 a0 = *(const half8*)&h1[1 - (P)][l15][baseA];             \
                half8 a1 = *(const half8*)&h1[1 - (P)][l15][baseB];             \
                half8 a2 = *(const half8*)&h2[(P)][l15][baseA];                 \
                half8 a3 = *(const half8*)&h2[(P)][l15][baseB];                 \
                floatx4 d0, d1, d2, d3;                                         \
                d0 = MFMA16F(a0, fr[0],  zacc);                                 \
                d1 = MFMA16F(a0, fr[4],  zacc);                                 \
                d2 = MFMA16F(a0, fr[8],  zacc);                                 \
                d3 = MFMA16F(a0, fr[12], zacc);                                 \
                d0 = MFMA16F(a1, fr[1],  d0);                                   \
                d1 = MFMA16F(a1, fr[5],  d1);                                   \
                d2 = MFMA16F(a1, fr[9],  d2);                                   \
                d3 = MFMA16F(a1, fr[13], d3);                                   \
                d0 = MFMA16F(a2, fr[2],  d0);                                   \
                d1 = MFMA16F(a2, fr[6],  d1);                                   \
                d2 = MFMA16F(a2, fr[10], d2);                                   \
                d3 = MFMA16F(a2, fr[14], d3);                                   \
                d0 = MFMA16F(a3, fr[3],  d0);                                   \
                d1 = MFMA16F(a3, fr[7],  d1);                                   \
                d2 = MFMA16F(a3, fr[11], d2);                                   \
                d3 = MFMA16F(a3, fr[15], d3);                                   \
                floatx4 f0, f1, f2, f3;                                         \
                GTAIL(d0, f0, -) GTAIL(d1, f1, -) GTAIL(d2, f2, +) GTAIL(d3, f3, -) \
                _Pragma("unroll")                                               \
                for (int r = 0; r < 4; r++) {                                   \
                    float tgs = fmaf(-4.0f * L2E, f2[r], 2.0f * L2E);           \
                    float cn  = fmaf(f1[r], cst[r], f0[r] * tgs);               \
                    cst[r] = cn;                                                \
                    float th = fmaf(-2.0f, rcp_fast(1.0f + exp2_fast(cn)), 1.0f); \
                    float hv = f3[r] * th;                                      \
                    hv = uok ? hv : (uc == 51 ? 1.0f : 0.f);                    \
                    int bb = q * 4 + r;                                         \
                    int wi = (((uc >> 1) + 4 * (bb >> 1)) & 31) * 2 + (uc & 1); \
                    ((unsigned short*)&h2[1 - (P)][bb][0])[wi] = f2h_bits(hv);  \
                }                                                               \
            }                                                                   \
        } else {                                                                \
            if ((IT) <= TT - 1) {                /* cell1 -> h1(IT) */          \
                float4 xn = {0.f, 0.f, 0.f, 0.f};                               \
                if (uc >= HH) xn = *(const float4*)&xb[((IT) + 1) * 16 + q * 4]; \
                half8 a0 = *(const half8*)&h1[1 - (P)][l15][baseA];             \
                half8 a1 = *(const half8*)&h1[1 - (P)][l15][baseB];             \
                floatx4 d0, d1, d2, d3;                                         \
                d0 = MFMA16F(a0, fr[0], zacc);                                  \
                d1 = MFMA16F(a0, fr[2], zacc);                                  \
                d2 = MFMA16F(a0, fr[4], zacc);                                  \
                d3 = MFMA16F(a0, fr[6], zacc);                                  \
                d0 = MFMA16F(a1, fr[1], d0);                                    \
                d1 = MFMA16F(a1, fr[3], d1);                                    \
                d2 = MFMA16F(a1, fr[5], d2);                                    \
                d3 = MFMA16F(a1, fr[7], d3);                                    \
                floatx4 f0, f1, f2, f3;                                         \
                GTAIL(d0, f0, -) GTAIL(d1, f1, -) GTAIL(d2, f2, +) GTAIL(d3, f3, -) \
                _Pragma("unroll")                                               \
                for (int r = 0; r < 4; r++) {                                   \
                    float tgs = fmaf(-4.0f * L2E, f2[r], 2.0f * L2E);           \
                    float cn  = fmaf(f1[r], cst[r], f0[r] * tgs);               \
                    cst[r] = cn;                                                \
                    float th = fmaf(-2.0f, rcp_fast(1.0f + exp2_fast(cn)), 1.0f); \
                    float hv = f3[r] * th;                                      \
                    hv = uok ? hv                                               \
                             : (uc == 51 ? 1.0f                                 \
                             : (uc == 52 ? xn[r]                                \
                             : (uc == 53 ? xn[r] - (float)(_Float16)xn[r] : 0.f))); \
                    int bb = q * 4 + r;                                         \
                    int wi = (((uc >> 1) + 4 * (bb >> 1)) & 31) * 2 + (uc & 1); \
                    ((unsigned short*)&h1[(P)][bb][0])[wi] = f2h_bits(hv);      \
                }                                                               \
            }                                                                   \
            if ((IT) >= 2 && (w - 4) == ((IT) & 3)) {   /* rotated head */      \
                half8 a2 = *(const half8*)&h2[(P)][l15][baseA];                 \
                half8 a3 = *(const half8*)&h2[(P)][l15][baseB];                 \
                floatx4 ho;                                                     \
                ho = MFMA16F(a2, fr[8], zacc);                                  \
                ho = MFMA16F(a3, fr[9], ho);                                    \
                if (l15 == 0) {                                                 \
                    _Pragma("unroll")                                           \
                    for (int r = 0; r < 4; r++)                                 \
                        out[(size_t)(b0g + q * 4 + r) * TT + ((IT) - 2)] = ho[r]; \
                }                                                               \
            }                                                                   \
        }                                                                       \
        __syncthreads();                                                        \
    } while (0)

    for (int itp = 0; itp < TT + 2; itp += 2) {
        STEP(itp, 0);
        STEP(itp + 1, 1);
    }
#undef STEP
#undef GTAIL
}

extern "C" void kernel_launch(void* const* d_in, const int* in_sizes, int n_in,
                              void* d_out, int out_size, void* d_ws, size_t ws_size,
                              hipStream_t stream) {
    const float* input = (const float*)d_in[0];
    const float* Wih1  = (const float*)d_in[1];
    const float* Whh1  = (const float*)d_in[2];
    const float* bih1  = (const float*)d_in[3];
    const float* bhh1  = (const float*)d_in[4];
    const float* Wih2  = (const float*)d_in[5];
    const float* Whh2  = (const float*)d_in[6];
    const float* bih2  = (const float*)d_in[7];
    const float* bhh2  = (const float*)d_in[8];
    const float* Wlin  = (const float*)d_in[9];
    const float* blin  = (const float*)d_in[10];

    uint4* frags = (uint4*)d_ws;            // 196 frags * 1 KiB
    int B = in_sizes[0] / TT;               // 4096

    lstm_prep<<<49, 256, 0, stream>>>(Whh1, Wih1, bih1, bhh1, Wih2, Whh2,
                                      bih2, bhh2, Wlin, blin, frags);
    lstm_main<<<B / NB, 512, 0, stream>>>(input, frags, (float*)d_out);
}

// Round 7
// 309.607 us; speedup vs baseline: 1.5058x; 1.0730x over previous
//
#include <hip/hip_runtime.h>

#define HH 51
#define TT 256
#define NB 16
#define L2E 1.442695041f

typedef __attribute__((ext_vector_type(8))) _Float16 half8;
typedef __attribute__((ext_vector_type(4))) float   floatx4;

#define MFMA16F(A,B,C) __builtin_amdgcn_mfma_f32_16x16x32_f16((A),(B),(C),0,0,0)

__device__ __forceinline__ float rcp_fast(float x) { return __builtin_amdgcn_rcpf(x); }
#if __has_builtin(__builtin_amdgcn_exp2f)
__device__ __forceinline__ float exp2_fast(float x) { return __builtin_amdgcn_exp2f(x); }
#else
__device__ __forceinline__ float exp2_fast(float x) { return __expf(0.69314718056f * x); }
#endif
__device__ __forceinline__ unsigned short f2h_bits(float v) {
    return __builtin_bit_cast(unsigned short, (_Float16)v);
}

// ------------- weight pre-pack: fp16 hi/lo fragments, K-column folding ---
// (UNCHANGED. Main kernel loads ONLY the hi fragments (hl=0).)
__global__ void lstm_prep(const float* __restrict__ Whh1, const float* __restrict__ Wih1,
                          const float* __restrict__ bih1, const float* __restrict__ bhh1,
                          const float* __restrict__ Wih2, const float* __restrict__ Whh2,
                          const float* __restrict__ bih2, const float* __restrict__ bhh2,
                          const float* __restrict__ Wlin, const float* __restrict__ blin,
                          uint4* __restrict__ frags) {
    int tid = blockIdx.x * blockDim.x + threadIdx.x;
    if (tid >= 196 * 64) return;
    int f = tid >> 6, lane = tid & 63;
    int n = lane & 15, qq = lane >> 4;
    int hl, s, tau, cell;
    if (f < 64)       { cell = 1; int r = f;       hl = r & 1; r >>= 1; s = r & 1; tau = r >> 1; }
    else if (f < 192) { cell = 2; int r = f - 64;  hl = r & 1; r >>= 1; s = r & 3; tau = r >> 2; }
    else              { cell = 3; int r = f - 192; hl = r & 1; s = r >> 1; tau = 0; }
    int g = tau >> 2, U = tau & 3, u = U * 16 + n;
    float sc = (cell == 3) ? 1.0f : ((g == 2) ? 2.0f * L2E : L2E);
    unsigned int dw[4];
    for (int d = 0; d < 4; d++) {
        unsigned int packed = 0;
        for (int e = 0; e < 2; e++) {
            int jj = d * 2 + e;
            int k = s * 32 + qq * 8 + jj;
            float val = 0.f;
            if (cell == 1) {
                if (u < HH) {
                    if (k < HH)       val = Whh1[(g * HH + u) * HH + k];
                    else if (k == 51) val = bih1[g * HH + u] + bhh1[g * HH + u];
                    else              val = Wih1[g * HH + u];   // k=52,53
                }
            } else if (cell == 2) {
                if (u < HH) {
                    if (k < 64) {
                        if (k < HH)       val = Wih2[(g * HH + u) * HH + k];
                        else if (k == 51) val = bih2[g * HH + u] + bhh2[g * HH + u];
                        // k=52,53 stay 0 (x pass-through)
                    } else {
                        int k2 = k - 64;
                        if (k2 < HH) val = Whh2[(g * HH + u) * HH + k2];
                    }
                }
            } else {
                if (n == 0) {
                    if (k < HH)       val = Wlin[k];
                    else if (k == 51) val = blin[0];
                }
            }
            val *= sc;
            _Float16 hi = (_Float16)val;
            unsigned short bits;
            if (hl) { float lo = val - (float)hi; bits = f2h_bits(lo); }
            else    { bits = __builtin_bit_cast(unsigned short, hi); }
            packed |= ((unsigned int)bits) << (16 * e);
        }
        dw[d] = packed;
    }
    frags[f * 64 + lane] = make_uint4(dw[0], dw[1], dw[2], dw[3]);
}

// -------------------------------------------------------------------------
// One-barrier skewed LSTM, single-fp16 weights (R6, 278us) + FUSED-RCP tail:
// Serial-per-SIMD model (validated r6): step = MFMA ~400 + VALU/trans ~1190
// + stall ~1000 cy. Trans ops dominate the busy term (~880cy; rcp/exp2
// ~11cy each wave64). exp2 count (5/elem) is irreducible; rcp 5/elem -> 2:
//   P = (1+ei)(1+eg); R = rcp((1+ef)P)  ->  f1 = R*P,  1/P = R*(1+ef)
//   i*g term: 2L2E*(eg-1)*R*(1+ef)      [== f0*tgs exactly]
//   o*tanh:   hv = (ec-1) * rcp((1+eo)(1+ec))   [== f3*th exactly]
// Overflow audit: |gate|<=~8 -> products <=1.2e14 finite; ec->{0,inf}
// limits reproduce original th=+-1 behavior. Rounding delta ~1ulp,
// invisible at the 2^-12 fp16-h floor. Everything else identical to R6.
// -------------------------------------------------------------------------
__launch_bounds__(512, 2)
__global__ void lstm_main(const float* __restrict__ input,
                          const uint4* __restrict__ frags,
                          float* __restrict__ out) {
    __shared__ __align__(16) unsigned int h1[2][16][36];
    __shared__ __align__(16) unsigned int h2[2][16][36];
    __shared__ __align__(16) float xb[(TT + 1) * 16];    // [t][b], row TT = 0

    const int tid  = threadIdx.x;
    const int lane = tid & 63;
    const int w    = tid >> 6;
    const int l15  = lane & 15;
    const int q    = lane >> 4;
    const int b0g  = blockIdx.x * NB;
    const bool c2w = (w < 4);
    const int U    = c2w ? w : (w - 4);
    const int uc   = U * 16 + l15;
    const bool uok = (uc < HH);

    for (int i = tid; i < 2 * 16 * 36; i += 512) {
        ((unsigned*)h1)[i] = 0; ((unsigned*)h2)[i] = 0;
    }
    for (int c = 0; c < 2; c++) {
        int flat = tid + c * 512;
        int b = flat >> 6, t0 = (flat & 63) * 4;
        float4 v = *(const float4*)&input[(size_t)(b0g + b) * TT + t0];
        xb[(t0 + 0) * 16 + b] = v.x; xb[(t0 + 1) * 16 + b] = v.y;
        xb[(t0 + 2) * 16 + b] = v.z; xb[(t0 + 3) * 16 + b] = v.w;
    }
    if (tid < 16) xb[TT * 16 + tid] = 0.f;
    __syncthreads();
    if (tid < 16) {                         // initial hooks in h1 parity 1
        int b = tid;
        int wi51 = ((25 + 4 * (b >> 1)) & 31) * 2 + 1;   // u=51 (bias col)
        int wi52 = ((26 + 4 * (b >> 1)) & 31) * 2 + 0;   // u=52 (x_hi)
        int wi53 = ((26 + 4 * (b >> 1)) & 31) * 2 + 1;   // u=53 (x_lo)
        ((unsigned short*)&h1[1][b][0])[wi51] = 0x3C00;  // fp16(1.0)
        float x0 = input[(size_t)(b0g + b) * TT];
        _Float16 xh = (_Float16)x0;
        ((unsigned short*)&h1[1][b][0])[wi52] = __builtin_bit_cast(unsigned short, xh);
        ((unsigned short*)&h1[1][b][0])[wi53] = f2h_bits(x0 - (float)xh);
    }

    // weight-stationary fragments -- HI ONLY
    half8 fr[16];
    if (c2w) {
#pragma unroll
        for (int g = 0; g < 4; g++) {
            int tau = g * 4 + U;
#pragma unroll
            for (int s = 0; s < 4; s++)
                fr[g * 4 + s] = __builtin_bit_cast(half8, frags[(64 + (tau * 4 + s) * 2) * 64 + lane]);
        }
    } else {
#pragma unroll
        for (int g = 0; g < 4; g++) {
            int tau = g * 4 + U;
#pragma unroll
            for (int s = 0; s < 2; s++)
                fr[g * 2 + s] = __builtin_bit_cast(half8, frags[((tau * 2 + s) * 2) * 64 + lane]);
        }
#pragma unroll
        for (int s = 0; s < 2; s++)         // head frags on ALL c1 waves
            fr[8 + s] = __builtin_bit_cast(half8, frags[(192 + s * 2) * 64 + lane]);
    }
    floatx4 zacc = {0.f, 0.f, 0.f, 0.f};
    float cst[4] = {0.f, 0.f, 0.f, 0.f};
    const int baseA = (q * 4 + 4 * (l15 >> 1)) & 31;
    const int baseB = (baseA + 16) & 31;

    __syncthreads();

// fused activation tail: 5 exp2 + 2 rcp per element (was 5 exp2 + 5 rcp)
#define FTAIL(D0, D1, D2, D3, HVA)                                              \
    _Pragma("unroll")                                                           \
    for (int r = 0; r < 4; r++) {                                               \
        float ei = exp2_fast(-(D0)[r]);                                         \
        float ef = exp2_fast(-(D1)[r]);                                         \
        float eg = exp2_fast( (D2)[r]);                                         \
        float eo = exp2_fast(-(D3)[r]);                                         \
        float Fv = 1.f + ef;                                                    \
        float Pv = (1.f + ei) * (1.f + eg);                                     \
        float Rv = rcp_fast(Fv * Pv);                                           \
        float f1v = Rv * Pv;                                                    \
        float tv  = fmaf(2.f * L2E, eg, -2.f * L2E);                            \
        float igt = tv * (Rv * Fv);                                             \
        float cn  = fmaf(f1v, cst[r], igt);                                     \
        cst[r] = cn;                                                            \
        float ec = exp2_fast(cn);                                               \
        float Ov = 1.f + eo;                                                    \
        float Sv = rcp_fast(fmaf(Ov, ec, Ov));                                  \
        (HVA)[r] = (ec - 1.f) * Sv;                                             \
    }

#define STEP(IT, P)                                                             \
    do {                                                                        \
        if (c2w) {                                                              \
            if ((IT) >= 1 && (IT) <= TT) {       /* cell2 -> h2(IT-1) */        \
                half8 a0 = *(const half8*)&h1[1 - (P)][l15][baseA];             \
                half8 a1 = *(const half8*)&h1[1 - (P)][l15][baseB];             \
                half8 a2 = *(const half8*)&h2[(P)][l15][baseA];                 \
                half8 a3 = *(const half8*)&h2[(P)][l15][baseB];                 \
                floatx4 d0, d1, d2, d3;                                         \
                d0 = MFMA16F(a0, fr[0],  zacc);                                 \
                d1 = MFMA16F(a0, fr[4],  zacc);                                 \
                d2 = MFMA16F(a0, fr[8],  zacc);                                 \
                d3 = MFMA16F(a0, fr[12], zacc);                                 \
                d0 = MFMA16F(a1, fr[1],  d0);                                   \
                d1 = MFMA16F(a1, fr[5],  d1);                                   \
                d2 = MFMA16F(a1, fr[9],  d2);                                   \
                d3 = MFMA16F(a1, fr[13], d3);                                   \
                d0 = MFMA16F(a2, fr[2],  d0);                                   \
                d1 = MFMA16F(a2, fr[6],  d1);                                   \
                d2 = MFMA16F(a2, fr[10], d2);                                   \
                d3 = MFMA16F(a2, fr[14], d3);                                   \
                d0 = MFMA16F(a3, fr[3],  d0);                                   \
                d1 = MFMA16F(a3, fr[7],  d1);                                   \
                d2 = MFMA16F(a3, fr[11], d2);                                   \
                d3 = MFMA16F(a3, fr[15], d3);                                   \
                float hv_s[4];                                                  \
                FTAIL(d0, d1, d2, d3, hv_s)                                     \
                _Pragma("unroll")                                               \
                for (int r = 0; r < 4; r++) {                                   \
                    float hv = uok ? hv_s[r] : (uc == 51 ? 1.0f : 0.f);         \
                    int bb = q * 4 + r;                                         \
                    int wi = (((uc >> 1) + 4 * (bb >> 1)) & 31) * 2 + (uc & 1); \
                    ((unsigned short*)&h2[1 - (P)][bb][0])[wi] = f2h_bits(hv);  \
                }                                                               \
            }                                                                   \
        } else {                                                                \
            if ((IT) <= TT - 1) {                /* cell1 -> h1(IT) */          \
                float4 xn = {0.f, 0.f, 0.f, 0.f};                               \
                if (uc >= HH) xn = *(const float4*)&xb[((IT) + 1) * 16 + q * 4]; \
                half8 a0 = *(const half8*)&h1[1 - (P)][l15][baseA];             \
                half8 a1 = *(const half8*)&h1[1 - (P)][l15][baseB];             \
                floatx4 d0, d1, d2, d3;                                         \
                d0 = MFMA16F(a0, fr[0], zacc);                                  \
                d1 = MFMA16F(a0, fr[2], zacc);                                  \
                d2 = MFMA16F(a0, fr[4], zacc);                                  \
                d3 = MFMA16F(a0, fr[6], zacc);                                  \
                d0 = MFMA16F(a1, fr[1], d0);                                    \
                d1 = MFMA16F(a1, fr[3], d1);                                    \
                d2 = MFMA16F(a1, fr[5], d2);                                    \
                d3 = MFMA16F(a1, fr[7], d3);                                    \
                float hv_s[4];                                                  \
                FTAIL(d0, d1, d2, d3, hv_s)                                     \
                _Pragma("unroll")                                               \
                for (int r = 0; r < 4; r++) {                                   \
                    float hv = uok ? hv_s[r]                                    \
                             : (uc == 51 ? 1.0f                                 \
                             : (uc == 52 ? xn[r]                                \
                             : (uc == 53 ? xn[r] - (float)(_Float16)xn[r] : 0.f))); \
                    int bb = q * 4 + r;                                         \
                    int wi = (((uc >> 1) + 4 * (bb >> 1)) & 31) * 2 + (uc & 1); \
                    ((unsigned short*)&h1[(P)][bb][0])[wi] = f2h_bits(hv);      \
                }                                                               \
            }                                                                   \
            if ((IT) >= 2 && (w - 4) == ((IT) & 3)) {   /* rotated head */      \
                half8 a2 = *(const half8*)&h2[(P)][l15][baseA];                 \
                half8 a3 = *(const half8*)&h2[(P)][l15][baseB];                 \
                floatx4 ho;                                                     \
                ho = MFMA16F(a2, fr[8], zacc);                                  \
                ho = MFMA16F(a3, fr[9], ho);                                    \
                if (l15 == 0) {                                                 \
                    _Pragma("unroll")                                           \
                    for (int r = 0; r < 4; r++)                                 \
                        out[(size_t)(b0g + q * 4 + r) * TT + ((IT) - 2)] = ho[r]; \
                }                                                               \
            }                                                                   \
        }                                                                       \
        __syncthreads();                                                        \
    } while (0)

    for (int itp = 0; itp < TT + 2; itp += 2) {
        STEP(itp, 0);
        STEP(itp + 1, 1);
    }
#undef STEP
#undef FTAIL
}

extern "C" void kernel_launch(void* const* d_in, const int* in_sizes, int n_in,
                              void* d_out, int out_size, void* d_ws, size_t ws_size,
                              hipStream_t stream) {
    const float* input = (const float*)d_in[0];
    const float* Wih1  = (const float*)d_in[1];
    const float* Whh1  = (const float*)d_in[2];
    const float* bih1  = (const float*)d_in[3];
    const float* bhh1  = (const float*)d_in[4];
    const float* Wih2  = (const float*)d_in[5];
    const float* Whh2  = (const float*)d_in[6];
    const float* bih2  = (const float*)d_in[7];
    const float* bhh2  = (const float*)d_in[8];
    const float* Wlin  = (const float*)d_in[9];
    const float* blin  = (const float*)d_in[10];

    uint4* frags = (uint4*)d_ws;            // 196 frags * 1 KiB
    int B = in_sizes[0] / TT;               // 4096

    lstm_prep<<<49, 256, 0, stream>>>(Whh1, Wih1, bih1, bhh1, Wih2, Whh2,
                                      bih2, bhh2, Wlin, blin, frags);
    lstm_main<<<B / NB, 512, 0, stream>>>(input, frags, (float*)d_out);
}